// Round 2
// baseline (279.382 us; speedup 1.0000x reference)
//
#include <hip/hip_runtime.h>
#include <stdint.h>

typedef float f32x4 __attribute__((ext_vector_type(4)));
typedef int   i32x4 __attribute__((ext_vector_type(4)));
typedef int   i32x8 __attribute__((ext_vector_type(8)));

// ---------------------------------------------------------------------------
// Fused amax: blocks [0,xblocks) reduce |x|, the rest reduce |w|.
// SIGNED atomicMax: |x| bit patterns are non-negative ints; the 0xAAAAAAAA
// ws poison is negative, so no memset/init dispatch is needed.
// ---------------------------------------------------------------------------
__global__ __launch_bounds__(256) void amax2_kernel(
    const float* __restrict__ x, int nx4,
    const float* __restrict__ w, int nw4,
    int xblocks, int* __restrict__ out) {
  const float4* src;
  int n4, j0, stride, slot;
  if ((int)blockIdx.x < xblocks) {
    src = (const float4*)x; n4 = nx4; slot = 0;
    j0 = blockIdx.x * blockDim.x + threadIdx.x;
    stride = xblocks * blockDim.x;
  } else {
    src = (const float4*)w; n4 = nw4; slot = 1;
    j0 = (blockIdx.x - xblocks) * blockDim.x + threadIdx.x;
    stride = (gridDim.x - xblocks) * blockDim.x;
  }
  float m = 0.f;
  for (int j = j0; j < n4; j += stride) {
    float4 v = src[j];
    m = fmaxf(m, fmaxf(fmaxf(fabsf(v.x), fabsf(v.y)),
                       fmaxf(fabsf(v.z), fabsf(v.w))));
  }
#pragma unroll
  for (int off = 32; off; off >>= 1)
    m = fmaxf(m, __shfl_down(m, off, 64));
  __shared__ float red[4];
  const int lane = threadIdx.x & 63;
  const int wv = threadIdx.x >> 6;
  if (lane == 0) red[wv] = m;
  __syncthreads();
  if (threadIdx.x == 0) {
    m = fmaxf(fmaxf(red[0], red[1]), fmaxf(red[2], red[3]));
    atomicMax(out + slot, (int)__float_as_uint(m));
  }
}

// ---------------------------------------------------------------------------
// Fused fp8 e4m3fn quantization for both tensors, bit-exact vs ml_dtypes:
//   inv_scale = max(amax/448, 1e-12)  (true division)
//   q = RNE(x / inv_scale)            (true division, v_cvt_pk_fp8_f32)
// ---------------------------------------------------------------------------
__global__ __launch_bounds__(256) void quant2_kernel(
    const float* __restrict__ x, unsigned char* __restrict__ qx, int nx4,
    const float* __restrict__ w, unsigned char* __restrict__ qw, int nw4,
    int xblocks, const unsigned* __restrict__ amax2) {
  const float4* src;
  unsigned* dst;
  int n4, j0, stride;
  float amax;
  if ((int)blockIdx.x < xblocks) {
    src = (const float4*)x; dst = (unsigned*)qx; n4 = nx4;
    amax = __uint_as_float(amax2[0]);
    j0 = blockIdx.x * blockDim.x + threadIdx.x;
    stride = xblocks * blockDim.x;
  } else {
    src = (const float4*)w; dst = (unsigned*)qw; n4 = nw4;
    amax = __uint_as_float(amax2[1]);
    j0 = (blockIdx.x - xblocks) * blockDim.x + threadIdx.x;
    stride = (gridDim.x - xblocks) * blockDim.x;
  }
  const float inv_scale = fmaxf(amax / 448.0f, 1e-12f);
  for (int j = j0; j < n4; j += stride) {
    float4 v = src[j];
    float a0 = v.x / inv_scale;
    float a1 = v.y / inv_scale;
    float a2 = v.z / inv_scale;
    float a3 = v.w / inv_scale;
    int p = 0;
    p = __builtin_amdgcn_cvt_pk_fp8_f32(a0, a1, p, false);  // bytes 0,1
    p = __builtin_amdgcn_cvt_pk_fp8_f32(a2, a3, p, true);   // bytes 2,3
    dst[j] = (unsigned)p;
  }
}

// ---------------------------------------------------------------------------
// MX-scaled fp8 GEMM, 256x256 tile, BK=128, 8-wave (2Mx4N), 4 regions/tile
// with FRAGMENT READS PIPELINED ONE REGION AHEAD (reads overlap MFMA on
// separate pipes), one s_barrier per region, one vmcnt(0) per tile draining
// loads issued 2-3 regions earlier.
//
// Cluster order (reorder vs round 1 so every frag group has a 1-region-free
// window before reuse, with zero extra double-buffer registers beyond the
// split af[8]):
//   C0: af0-3 x bf0-1   | read bf2-3(t)
//   C1: af0-3 x bf2-3   | read af4-7(t)             | vmcnt(0) at end
//   C2: af4-7 x bf0-1   | read af0-3(t+1) ; stage B(t+2)
//   C3: af4-7 x bf2-3   | read bf0-1(t+1) ; stage A(t+2)
//
// Safety rule (derived): a read issued in region R is lgkm-drained at R+1's
// entry, which precedes R+1's end barrier; so a stage in region R+2 may
// overwrite it. B(t+2)@C2 vs B(t) reads issued C0 (dist 2) OK; A(t+2)@C3 vs
// A(t) reads issued C1 (dist 2) OK. RAW: A(t+1)/B(t+1) staged at C3(t-1)/
// C2(t-1), drained by vmcnt(0)@C1(t)-end + barrier before first use at
// C2(t)/C3(t). Prologue reproduces the steady state {A(1),B(1) in flight}.
//
// LDS swizzle + fragment layout identical to the numerically verified
// round-1 kernel (chunk c_s holds global chunk c_s ^ (row&7), reads XOR the
// same; MX unit scale 0x7F -> exact fp8 product).
// ---------------------------------------------------------------------------
#define BM 256
#define BN 256
#define BK 128
#define GEMM_LDS_BYTES (4 * 32768)  // 2 bufs x (A 32KB + B 32KB)

__device__ __forceinline__ void load_lds16(const void* g, void* l) {
  __builtin_amdgcn_global_load_lds(
      (const __attribute__((address_space(1))) unsigned int*)g,
      (__attribute__((address_space(3))) unsigned int*)l, 16, 0, 0);
}

__global__ __launch_bounds__(512, 2) void gemm_fp8_kernel(
    const unsigned char* __restrict__ Aq,   // [T,K] fp8
    const unsigned char* __restrict__ Bq,   // [N,K] fp8 (W quantized, row-major)
    const float* __restrict__ bias,         // [N]
    const unsigned* __restrict__ amax2,     // [0]=amax(x), [1]=amax(w) bits
    float* __restrict__ out,                // [T,N]
    int T, int N, int K) {
  extern __shared__ unsigned char smem[];
  unsigned char* sA = smem;            // [2][256*128]
  unsigned char* sB = smem + 65536;    // [2][256*128]

  const int tid  = threadIdx.x;
  const int lane = tid & 63;
  const int wave = tid >> 6;
  const int wm = (wave >> 2) * 128;   // 2 M-warps
  const int wn = (wave & 3) * 64;     // 4 N-warps

  // XCD-aware bijective swizzle (nwg=256 divisible by 8).
  int lin = (int)(blockIdx.y * gridDim.x + blockIdx.x);
  const int nwg = (int)(gridDim.x * gridDim.y);
  if ((nwg & 7) == 0) lin = (lin & 7) * (nwg >> 3) + (lin >> 3);
  const long m0 = (long)(lin / (int)gridDim.x) * BM;
  const long n0 = (long)(lin % (int)gridDim.x) * BN;

  const long Kl = (long)K;

  // Staging geometry: thread t covers LDS rows {t>>3, +64, +128, +192},
  // stored chunk c_s = t&7, fetching global chunk c_s ^ (row&7).
  const int row_s = tid >> 3;                       // 0..63
  const int scol  = ((tid & 7) ^ (row_s & 7)) << 4; // swizzled source chunk
  const int t16   = tid << 4;                       // linear LDS dest slot

  // Fragment-read geometry (identical to verified round-1 kernel).
  const int lm = lane & 15;
  const int qh = lane >> 4;
  const int c0 = ((qh * 2)     ^ (lm & 7)) << 4;
  const int c1 = ((qh * 2 + 1) ^ (lm & 7)) << 4;

  auto STAGE_A = [&](int Ts) {  // full 256-row A K-slice, 4 gload_lds
    const unsigned char* g = Aq + (m0 + row_s) * Kl + (long)Ts * BK + scol;
    unsigned char* l = sA + ((Ts & 1) << 15) + t16;
    load_lds16(g, l);
    load_lds16(g +  64 * Kl, l + 8192);
    load_lds16(g + 128 * Kl, l + 16384);
    load_lds16(g + 192 * Kl, l + 24576);
  };
  auto STAGE_B = [&](int Ts) {
    const unsigned char* g = Bq + (n0 + row_s) * Kl + (long)Ts * BK + scol;
    unsigned char* l = sB + ((Ts & 1) << 15) + t16;
    load_lds16(g, l);
    load_lds16(g +  64 * Kl, l + 8192);
    load_lds16(g + 128 * Kl, l + 16384);
    load_lds16(g + 192 * Kl, l + 24576);
  };
  auto LDA = [&](const unsigned char* base, int mt) {
    const unsigned char* p = base + (wm + mt * 16 + lm) * BK;
    i32x4 lo = *(const i32x4*)(p + c0);
    i32x4 hi = *(const i32x4*)(p + c1);
    return (i32x8){lo.x, lo.y, lo.z, lo.w, hi.x, hi.y, hi.z, hi.w};
  };
  auto LDB = [&](const unsigned char* base, int nt) {
    const unsigned char* p = base + (wn + nt * 16 + lm) * BK;
    i32x4 lo = *(const i32x4*)(p + c0);
    i32x4 hi = *(const i32x4*)(p + c1);
    return (i32x8){lo.x, lo.y, lo.z, lo.w, hi.x, hi.y, hi.z, hi.w};
  };

  f32x4 acc[8][4];
#pragma unroll
  for (int i = 0; i < 8; ++i)
#pragma unroll
    for (int j = 0; j < 4; ++j) acc[i][j] = (f32x4){0.f, 0.f, 0.f, 0.f};

  const int nt = K / BK;  // 16 for K=2048 (assumes nt >= 2)

  // Prologue: tile0 A+B (8 loads), then B(1) (4 loads, = C2(-1)'s stage).
  STAGE_A(0); STAGE_B(0);
  STAGE_B(1);
  asm volatile("s_waitcnt vmcnt(4)" ::: "memory");  // tile0 landed
  __builtin_amdgcn_s_barrier();

  i32x8 af[8], bf[4];
  // Pre-read C0(0)'s fragments (= C2/C3(-1)'s pipelined reads).
  af[0] = LDA(sA, 0); af[1] = LDA(sA, 1); af[2] = LDA(sA, 2); af[3] = LDA(sA, 3);
  bf[0] = LDB(sB, 0); bf[1] = LDB(sB, 1);
  STAGE_A(1);  // = C3(-1)'s stage

#define MFMA(ai, bj, ci, cj)                                            \
  acc[ci][cj] = __builtin_amdgcn_mfma_scale_f32_16x16x128_f8f6f4(       \
      af[ai], bf[bj], acc[ci][cj], 0, 0, 0, 0x7f7f7f7f, 0, 0x7f7f7f7f)

  for (int t = 0; t < nt; ++t) {
    const unsigned char* a  = sA + ((t & 1) << 15);
    const unsigned char* b  = sB + ((t & 1) << 15);
    const unsigned char* a1 = sA + (((t + 1) & 1) << 15);
    const unsigned char* b1 = sB + (((t + 1) & 1) << 15);

    // ---- C0: af0-3 x bf0-1 | read bf2-3(t)
    asm volatile("s_waitcnt lgkmcnt(0)");
    __builtin_amdgcn_sched_barrier(0);
    __builtin_amdgcn_s_setprio(1);
    bf[2] = LDB(b, 2); bf[3] = LDB(b, 3);
    MFMA(0, 0, 0, 0); MFMA(0, 1, 0, 1);
    MFMA(1, 0, 1, 0); MFMA(1, 1, 1, 1);
    MFMA(2, 0, 2, 0); MFMA(2, 1, 2, 1);
    MFMA(3, 0, 3, 0); MFMA(3, 1, 3, 1);
    __builtin_amdgcn_s_setprio(0);
    __builtin_amdgcn_s_barrier();

    // ---- C1: af0-3 x bf2-3 | read af4-7(t) | vmcnt(0) (drains A(t+1)
    // staged C3(t-1) and B(t+1) staged C2(t-1) -- 2-3 regions old)
    asm volatile("s_waitcnt lgkmcnt(0)");
    __builtin_amdgcn_sched_barrier(0);
    __builtin_amdgcn_s_setprio(1);
    af[4] = LDA(a, 4); af[5] = LDA(a, 5); af[6] = LDA(a, 6); af[7] = LDA(a, 7);
    MFMA(0, 2, 0, 2); MFMA(0, 3, 0, 3);
    MFMA(1, 2, 1, 2); MFMA(1, 3, 1, 3);
    MFMA(2, 2, 2, 2); MFMA(2, 3, 2, 3);
    MFMA(3, 2, 3, 2); MFMA(3, 3, 3, 3);
    __builtin_amdgcn_s_setprio(0);
    asm volatile("s_waitcnt vmcnt(0)" ::: "memory");
    __builtin_amdgcn_s_barrier();

    // ---- C2: af4-7 x bf0-1 | read af0-3(t+1); stage B(t+2)
    asm volatile("s_waitcnt lgkmcnt(0)");
    __builtin_amdgcn_sched_barrier(0);
    __builtin_amdgcn_s_setprio(1);
    if (t + 1 < nt) {
      af[0] = LDA(a1, 0); af[1] = LDA(a1, 1);
      af[2] = LDA(a1, 2); af[3] = LDA(a1, 3);
    }
    if (t + 2 < nt) STAGE_B(t + 2);
    MFMA(4, 0, 4, 0); MFMA(4, 1, 4, 1);
    MFMA(5, 0, 5, 0); MFMA(5, 1, 5, 1);
    MFMA(6, 0, 6, 0); MFMA(6, 1, 6, 1);
    MFMA(7, 0, 7, 0); MFMA(7, 1, 7, 1);
    __builtin_amdgcn_s_setprio(0);
    __builtin_amdgcn_s_barrier();

    // ---- C3: af4-7 x bf2-3 | read bf0-1(t+1); stage A(t+2)
    asm volatile("s_waitcnt lgkmcnt(0)");
    __builtin_amdgcn_sched_barrier(0);
    __builtin_amdgcn_s_setprio(1);
    if (t + 1 < nt) { bf[0] = LDB(b1, 0); bf[1] = LDB(b1, 1); }
    if (t + 2 < nt) STAGE_A(t + 2);
    MFMA(4, 2, 4, 2); MFMA(4, 3, 4, 3);
    MFMA(5, 2, 5, 2); MFMA(5, 3, 5, 3);
    MFMA(6, 2, 6, 2); MFMA(6, 3, 6, 3);
    MFMA(7, 2, 7, 2); MFMA(7, 3, 7, 3);
    __builtin_amdgcn_s_setprio(0);
    __builtin_amdgcn_s_barrier();
  }
#undef MFMA

  // Epilogue: C/D layout col = lane&15, row = (lane>>4)*4 + reg.
  const float fsx = fmaxf(__uint_as_float(amax2[0]) / 448.0f, 1e-12f);
  const float fsw = fmaxf(__uint_as_float(amax2[1]) / 448.0f, 1e-12f);
  const float scale = fsx * fsw;
  const int rbase = qh * 4;
  float bv[4];
#pragma unroll
  for (int j = 0; j < 4; ++j) bv[j] = bias[n0 + wn + j * 16 + lm];
#pragma unroll
  for (int mt = 0; mt < 8; ++mt) {
#pragma unroll
    for (int r = 0; r < 4; ++r) {
      const long row = m0 + wm + mt * 16 + rbase + r;
      float* orow = out + row * (long)N + n0 + wn;
#pragma unroll
      for (int j = 0; j < 4; ++j)
        orow[j * 16 + lm] = acc[mt][j][r] * scale + bv[j];
    }
  }
}

// ---------------------------------------------------------------------------
extern "C" void kernel_launch(void* const* d_in, const int* in_sizes, int n_in,
                              void* d_out, int out_size, void* d_ws, size_t ws_size,
                              hipStream_t stream) {
  const float* x = (const float*)d_in[0];       // [4,2048,2048] f32
  const float* w = (const float*)d_in[1];       // [2048,2048]   f32
  const float* bias = (const float*)d_in[2];    // [2048]        f32
  float* out = (float*)d_out;

  const int N = in_sizes[2];        // 2048
  const int K = in_sizes[1] / N;    // 2048
  const int T = in_sizes[0] / K;    // 8192

  unsigned* amax2 = (unsigned*)d_ws;                         // 2 slots
  unsigned char* qx = (unsigned char*)d_ws + 256;            // T*K fp8
  unsigned char* qw = qx + (size_t)T * K;                    // N*K fp8

  const int XB = 1024;  // blocks for the x-partition (x is 4x w's size)
  const int WB = 256;
  amax2_kernel<<<XB + WB, 256, 0, stream>>>(x, T * K / 4, w, N * K / 4, XB,
                                            (int*)amax2);
  quant2_kernel<<<XB + WB, 256, 0, stream>>>(x, qx, T * K / 4, w, qw, N * K / 4,
                                             XB, amax2);

  // 128 KiB dynamic LDS (> 64 KiB static limit) -> opt in once.
  static bool lds_attr_set = false;
  if (!lds_attr_set) {
    (void)hipFuncSetAttribute((const void*)gemm_fp8_kernel,
                              hipFuncAttributeMaxDynamicSharedMemorySize,
                              GEMM_LDS_BYTES);
    lds_attr_set = true;
  }
  dim3 grid(N / BN, T / BM);  // (8, 32) = 256 blocks = 1/CU
  gemm_fp8_kernel<<<grid, 512, GEMM_LDS_BYTES, stream>>>(qx, qw, bias, amax2,
                                                         out, T, N, K);
}

// Round 3
// 185.216 us; speedup vs baseline: 1.5084x; 1.5084x over previous
//
#include <hip/hip_runtime.h>
#include <stdint.h>

typedef float f32x4 __attribute__((ext_vector_type(4)));
typedef int   i32x4 __attribute__((ext_vector_type(4)));
typedef int   i32x8 __attribute__((ext_vector_type(8)));

// ---------------------------------------------------------------------------
// Fused amax: blocks [0,xblocks) reduce |x|, the rest reduce |w|.
// SIGNED atomicMax: |x| bit patterns are non-negative ints; the 0xAAAAAAAA
// ws poison is negative, so no memset/init dispatch is needed.
// ---------------------------------------------------------------------------
__global__ __launch_bounds__(256) void amax2_kernel(
    const float* __restrict__ x, int nx4,
    const float* __restrict__ w, int nw4,
    int xblocks, int* __restrict__ out) {
  const float4* src;
  int n4, j0, stride, slot;
  if ((int)blockIdx.x < xblocks) {
    src = (const float4*)x; n4 = nx4; slot = 0;
    j0 = blockIdx.x * blockDim.x + threadIdx.x;
    stride = xblocks * blockDim.x;
  } else {
    src = (const float4*)w; n4 = nw4; slot = 1;
    j0 = (blockIdx.x - xblocks) * blockDim.x + threadIdx.x;
    stride = (gridDim.x - xblocks) * blockDim.x;
  }
  float m = 0.f;
  for (int j = j0; j < n4; j += stride) {
    float4 v = src[j];
    m = fmaxf(m, fmaxf(fmaxf(fabsf(v.x), fabsf(v.y)),
                       fmaxf(fabsf(v.z), fabsf(v.w))));
  }
#pragma unroll
  for (int off = 32; off; off >>= 1)
    m = fmaxf(m, __shfl_down(m, off, 64));
  __shared__ float red[4];
  const int lane = threadIdx.x & 63;
  const int wv = threadIdx.x >> 6;
  if (lane == 0) red[wv] = m;
  __syncthreads();
  if (threadIdx.x == 0) {
    m = fmaxf(fmaxf(red[0], red[1]), fmaxf(red[2], red[3]));
    atomicMax(out + slot, (int)__float_as_uint(m));
  }
}

// ---------------------------------------------------------------------------
// Fused fp8 e4m3fn quantization for both tensors, bit-exact vs ml_dtypes:
//   inv_scale = max(amax/448, 1e-12)  (true division)
//   q = RNE(x / inv_scale)            (true division, v_cvt_pk_fp8_f32)
// ---------------------------------------------------------------------------
__global__ __launch_bounds__(256) void quant2_kernel(
    const float* __restrict__ x, unsigned char* __restrict__ qx, int nx4,
    const float* __restrict__ w, unsigned char* __restrict__ qw, int nw4,
    int xblocks, const unsigned* __restrict__ amax2) {
  const float4* src;
  unsigned* dst;
  int n4, j0, stride;
  float amax;
  if ((int)blockIdx.x < xblocks) {
    src = (const float4*)x; dst = (unsigned*)qx; n4 = nx4;
    amax = __uint_as_float(amax2[0]);
    j0 = blockIdx.x * blockDim.x + threadIdx.x;
    stride = xblocks * blockDim.x;
  } else {
    src = (const float4*)w; dst = (unsigned*)qw; n4 = nw4;
    amax = __uint_as_float(amax2[1]);
    j0 = (blockIdx.x - xblocks) * blockDim.x + threadIdx.x;
    stride = (gridDim.x - xblocks) * blockDim.x;
  }
  const float inv_scale = fmaxf(amax / 448.0f, 1e-12f);
  for (int j = j0; j < n4; j += stride) {
    float4 v = src[j];
    float a0 = v.x / inv_scale;
    float a1 = v.y / inv_scale;
    float a2 = v.z / inv_scale;
    float a3 = v.w / inv_scale;
    int p = 0;
    p = __builtin_amdgcn_cvt_pk_fp8_f32(a0, a1, p, false);  // bytes 0,1
    p = __builtin_amdgcn_cvt_pk_fp8_f32(a2, a3, p, true);   // bytes 2,3
    dst[j] = (unsigned)p;
  }
}

// ---------------------------------------------------------------------------
// MX-scaled fp8 GEMM, 256x256 tile, BK=128, 8-wave (2Mx4N), 4 phases/tile
// with a SINGLE barrier per phase:
//   phase q: { frag ds_reads(q) ; stage issues ; s_waitcnt lgkmcnt(0) ;
//              sched_barrier ; setprio(1) ; 8 MFMA ; setprio(0) ; s_barrier }
//
// vs round 1 (two barriers/phase -> CU-wide lockstep: LDS-read time and MFMA
// time ADD): with one barrier, the 2 waves/SIMD desynchronize inside the
// region, so one wave's ds_reads overlap the other's MFMA cluster (LDS pipe
// and matrix pipe are separate). Register pressure is round-1's proven
// level: af[4]+bf[4] = 64 frag VGPRs + acc 128 (round 2's af[8] spilled ->
// 459 MB scratch writes; reverted).
//
// Phase read/stage map (reads for tile t cannot start before q0(t): A(t) and
// B(t) only fully drain at the vmcnt(4) ending tile t-1):
//   q0: read af0-3(t), bf0-1(t) | stage A(t+1,h0)
//   q1: read bf2-3(t)           | stage A(t+1,h1)
//   q2: read af4-7(t)           | stage B(t+2,h0)
//   q3: (no reads)              | stage B(t+2,h1) | vmcnt(4) | barrier
//
// Safety (single-barrier versions of the round-1 arguments):
//   - reads issued in phase q drain at q's own lgkmcnt(0), BEFORE q's end
//     barrier -> a stage in any later phase may overwrite them.
//     WAR: A(t+1)@q0(t) vs af4-7(t-1) reads (drained q2(t-1))  : dist 2 OK
//          B(t+2)@q2(t) vs bf2-3(t)   reads (drained q1(t))    : dist 1 OK
//   - RAW: vmcnt(4) at q3(t) end leaves only B(t+2)'s 4 loads outstanding
//     -> A(t+1), B(t+1) landed; barrier makes them CU-visible for q0(t+1).
//     Steady state at tile entry: B(t+1)'s 4 loads in flight (prologue
//     reproduces it).
//
// LDS swizzle + fragment layout identical to the numerically verified
// round-1 kernel (chunk c_s holds global chunk c_s ^ (row&7), reads XOR the
// same; MX unit scale 0x7F -> exact fp8 product).
// ---------------------------------------------------------------------------
#define BM 256
#define BN 256
#define BK 128
#define GEMM_LDS_BYTES (4 * 32768)  // 2 bufs x (A 32KB + B 32KB)

__device__ __forceinline__ void load_lds16(const void* g, void* l) {
  __builtin_amdgcn_global_load_lds(
      (const __attribute__((address_space(1))) unsigned int*)g,
      (__attribute__((address_space(3))) unsigned int*)l, 16, 0, 0);
}

__global__ __launch_bounds__(512, 2) void gemm_fp8_kernel(
    const unsigned char* __restrict__ Aq,   // [T,K] fp8
    const unsigned char* __restrict__ Bq,   // [N,K] fp8 (W quantized, row-major)
    const float* __restrict__ bias,         // [N]
    const unsigned* __restrict__ amax2,     // [0]=amax(x), [1]=amax(w) bits
    float* __restrict__ out,                // [T,N]
    int T, int N, int K) {
  extern __shared__ unsigned char smem[];
  unsigned char* sA = smem;            // [2][256*128]
  unsigned char* sB = smem + 65536;    // [2][256*128]

  const int tid  = threadIdx.x;
  const int lane = tid & 63;
  const int wave = tid >> 6;
  const int wm = (wave >> 2) * 128;   // 2 M-warps
  const int wn = (wave & 3) * 64;     // 4 N-warps

  // XCD-aware bijective swizzle (nwg=256 divisible by 8).
  int lin = (int)(blockIdx.y * gridDim.x + blockIdx.x);
  const int nwg = (int)(gridDim.x * gridDim.y);
  if ((nwg & 7) == 0) lin = (lin & 7) * (nwg >> 3) + (lin >> 3);
  const long m0 = (long)(lin / (int)gridDim.x) * BM;
  const long n0 = (long)(lin % (int)gridDim.x) * BN;

  const long Kl = (long)K;

  // Staging geometry: thread t covers LDS rows {t>>3, +64}, stored chunk
  // c_s = t&7, fetching global chunk c_s ^ (row&7). One STAGE_X(h) = 2
  // gload_lds = one 128-row half-tile (16 KB).
  const int row_s = tid >> 3;                       // 0..63
  const int scol  = ((tid & 7) ^ (row_s & 7)) << 4; // swizzled source chunk
  const int t16   = tid << 4;                       // linear LDS dest slot

  // Fragment-read geometry (identical to verified round-1 kernel).
  const int lm = lane & 15;
  const int qh = lane >> 4;
  const int c0 = ((qh * 2)     ^ (lm & 7)) << 4;
  const int c1 = ((qh * 2 + 1) ^ (lm & 7)) << 4;

  auto STAGE_A = [&](int Ts, int h) {  // h: 0 = rows 0..127, 1 = rows 128..255
    const unsigned char* g = Aq + (m0 + h * 128 + row_s) * Kl + (long)Ts * BK + scol;
    unsigned char* l = sA + ((Ts & 1) << 15) + (h << 14) + t16;
    load_lds16(g, l);
    load_lds16(g + 64 * Kl, l + 8192);
  };
  auto STAGE_B = [&](int Ts, int h) {
    const unsigned char* g = Bq + (n0 + h * 128 + row_s) * Kl + (long)Ts * BK + scol;
    unsigned char* l = sB + ((Ts & 1) << 15) + (h << 14) + t16;
    load_lds16(g, l);
    load_lds16(g + 64 * Kl, l + 8192);
  };
  auto LDA = [&](const unsigned char* base, int mt) {
    const unsigned char* p = base + (wm + mt * 16 + lm) * BK;
    i32x4 lo = *(const i32x4*)(p + c0);
    i32x4 hi = *(const i32x4*)(p + c1);
    return (i32x8){lo.x, lo.y, lo.z, lo.w, hi.x, hi.y, hi.z, hi.w};
  };
  auto LDB = [&](const unsigned char* base, int nt) {
    const unsigned char* p = base + (wn + nt * 16 + lm) * BK;
    i32x4 lo = *(const i32x4*)(p + c0);
    i32x4 hi = *(const i32x4*)(p + c1);
    return (i32x8){lo.x, lo.y, lo.z, lo.w, hi.x, hi.y, hi.z, hi.w};
  };

  f32x4 acc[8][4];
#pragma unroll
  for (int i = 0; i < 8; ++i)
#pragma unroll
    for (int j = 0; j < 4; ++j) acc[i][j] = (f32x4){0.f, 0.f, 0.f, 0.f};

  const int nt = K / BK;  // 16 for K=2048 (assumes nt >= 2)

  // Prologue: tile0 fully + tile1 B-halves (6 stages = 12 loads); wait until
  // only tile1's B (4 loads) may be outstanding -> tile0 landed.
  STAGE_B(0, 0); STAGE_B(0, 1); STAGE_A(0, 0); STAGE_A(0, 1);
  STAGE_B(1, 0); STAGE_B(1, 1);
  asm volatile("s_waitcnt vmcnt(4)" ::: "memory");
  __builtin_amdgcn_s_barrier();

  i32x8 af[4], bf[4];
  for (int t = 0; t < nt; ++t) {
    const unsigned char* a = sA + ((t & 1) << 15);
    const unsigned char* b = sB + ((t & 1) << 15);

    // -------- q0: read af0-3 + bf0-1 | stage A(t+1,h0) | MFMA | barrier
    af[0] = LDA(a, 0); af[1] = LDA(a, 1); af[2] = LDA(a, 2); af[3] = LDA(a, 3);
    bf[0] = LDB(b, 0); bf[1] = LDB(b, 1);
    if (t + 1 < nt) STAGE_A(t + 1, 0);
    asm volatile("s_waitcnt lgkmcnt(0)");
    __builtin_amdgcn_sched_barrier(0);
    __builtin_amdgcn_s_setprio(1);
#pragma unroll
    for (int i = 0; i < 4; ++i)
#pragma unroll
      for (int j = 0; j < 2; ++j)
        acc[i][j] = __builtin_amdgcn_mfma_scale_f32_16x16x128_f8f6f4(
            af[i], bf[j], acc[i][j], 0, 0, 0, 0x7f7f7f7f, 0, 0x7f7f7f7f);
    __builtin_amdgcn_s_setprio(0);
    __builtin_amdgcn_s_barrier();

    // -------- q1: read bf2-3 | stage A(t+1,h1) | MFMA | barrier
    bf[2] = LDB(b, 2); bf[3] = LDB(b, 3);
    if (t + 1 < nt) STAGE_A(t + 1, 1);
    asm volatile("s_waitcnt lgkmcnt(0)");
    __builtin_amdgcn_sched_barrier(0);
    __builtin_amdgcn_s_setprio(1);
#pragma unroll
    for (int i = 0; i < 4; ++i)
#pragma unroll
      for (int j = 0; j < 2; ++j)
        acc[i][2 + j] = __builtin_amdgcn_mfma_scale_f32_16x16x128_f8f6f4(
            af[i], bf[2 + j], acc[i][2 + j], 0, 0, 0, 0x7f7f7f7f, 0, 0x7f7f7f7f);
    __builtin_amdgcn_s_setprio(0);
    __builtin_amdgcn_s_barrier();

    // -------- q2: read af4-7 | stage B(t+2,h0) | MFMA | barrier
    af[0] = LDA(a, 4); af[1] = LDA(a, 5); af[2] = LDA(a, 6); af[3] = LDA(a, 7);
    if (t + 2 < nt) STAGE_B(t + 2, 0);
    asm volatile("s_waitcnt lgkmcnt(0)");
    __builtin_amdgcn_sched_barrier(0);
    __builtin_amdgcn_s_setprio(1);
#pragma unroll
    for (int i = 0; i < 4; ++i)
#pragma unroll
      for (int j = 0; j < 2; ++j)
        acc[4 + i][j] = __builtin_amdgcn_mfma_scale_f32_16x16x128_f8f6f4(
            af[i], bf[j], acc[4 + i][j], 0, 0, 0, 0x7f7f7f7f, 0, 0x7f7f7f7f);
    __builtin_amdgcn_s_setprio(0);
    __builtin_amdgcn_s_barrier();

    // -------- q3: stage B(t+2,h1) | MFMA | vmcnt(4) | barrier.
    // vmcnt(4) leaves only B(t+2)'s 4 loads in flight -> A(t+1) (staged
    // q0/q1) and B(t+1) (staged last tile) have landed for q0(t+1).
    if (t + 2 < nt) STAGE_B(t + 2, 1);
    __builtin_amdgcn_s_setprio(1);
#pragma unroll
    for (int i = 0; i < 4; ++i)
#pragma unroll
      for (int j = 0; j < 2; ++j)
        acc[4 + i][2 + j] = __builtin_amdgcn_mfma_scale_f32_16x16x128_f8f6f4(
            af[i], bf[2 + j], acc[4 + i][2 + j], 0, 0, 0, 0x7f7f7f7f, 0, 0x7f7f7f7f);
    __builtin_amdgcn_s_setprio(0);
    asm volatile("s_waitcnt vmcnt(4)" ::: "memory");
    __builtin_amdgcn_s_barrier();
  }

  // Epilogue: C/D layout col = lane&15, row = (lane>>4)*4 + reg.
  const float fsx = fmaxf(__uint_as_float(amax2[0]) / 448.0f, 1e-12f);
  const float fsw = fmaxf(__uint_as_float(amax2[1]) / 448.0f, 1e-12f);
  const float scale = fsx * fsw;
  const int rbase = qh * 4;
  float bv[4];
#pragma unroll
  for (int j = 0; j < 4; ++j) bv[j] = bias[n0 + wn + j * 16 + lm];
#pragma unroll
  for (int mt = 0; mt < 8; ++mt) {
#pragma unroll
    for (int r = 0; r < 4; ++r) {
      const long row = m0 + wm + mt * 16 + rbase + r;
      float* orow = out + row * (long)N + n0 + wn;
#pragma unroll
      for (int j = 0; j < 4; ++j)
        orow[j * 16 + lm] = acc[mt][j][r] * scale + bv[j];
    }
  }
}

// ---------------------------------------------------------------------------
extern "C" void kernel_launch(void* const* d_in, const int* in_sizes, int n_in,
                              void* d_out, int out_size, void* d_ws, size_t ws_size,
                              hipStream_t stream) {
  const float* x = (const float*)d_in[0];       // [4,2048,2048] f32
  const float* w = (const float*)d_in[1];       // [2048,2048]   f32
  const float* bias = (const float*)d_in[2];    // [2048]        f32
  float* out = (float*)d_out;

  const int N = in_sizes[2];        // 2048
  const int K = in_sizes[1] / N;    // 2048
  const int T = in_sizes[0] / K;    // 8192

  unsigned* amax2 = (unsigned*)d_ws;                         // 2 slots
  unsigned char* qx = (unsigned char*)d_ws + 256;            // T*K fp8
  unsigned char* qw = qx + (size_t)T * K;                    // N*K fp8

  const int XB = 1024;  // blocks for the x-partition (x is 4x w's size)
  const int WB = 256;
  amax2_kernel<<<XB + WB, 256, 0, stream>>>(x, T * K / 4, w, N * K / 4, XB,
                                            (int*)amax2);
  quant2_kernel<<<XB + WB, 256, 0, stream>>>(x, qx, T * K / 4, w, qw, N * K / 4,
                                             XB, amax2);

  // 128 KiB dynamic LDS (> 64 KiB static limit) -> opt in once.
  static bool lds_attr_set = false;
  if (!lds_attr_set) {
    (void)hipFuncSetAttribute((const void*)gemm_fp8_kernel,
                              hipFuncAttributeMaxDynamicSharedMemorySize,
                              GEMM_LDS_BYTES);
    lds_attr_set = true;
  }
  dim3 grid(N / BN, T / BM);  // (8, 32) = 256 blocks = 1/CU
  gemm_fp8_kernel<<<grid, 512, GEMM_LDS_BYTES, stream>>>(qx, qw, bias, amax2,
                                                         out, T, N, K);
}